// Round 5
// baseline (781.455 us; speedup 1.0000x reference)
//
#include <hip/hip_runtime.h>
#include <hip/hip_bf16.h>

// MultiHeadAttention  B=4, L=1024, H=16, U=64, D_IN=1024, D_MODEL=1024
// Round 5: 4 q-tiles per block (1024 threads) to amortize the K panel.
//   Theory: attn_fused is L2->L1 read-path bound (K panel 256 KB re-read by
//   every 16-row q-block; 1.6 GB total L2 reads, ~6.3 MB/CU, invisible to
//   FETCH_SIZE). Block = 64 q-rows, 16 waves = (qi 0..3) x (ki 0..3); the 4
//   waves sharing ki issue identical K addresses on the same SIMD -> L1
//   dedups 4x. Same for vhT in ctx (4 waves per ui). Per-wave code identical
//   to round 4 (lg[16] registers, lane-local softmax, paired full-line attn
//   stores). P LDS 128 KB (64 rows), 1 block/CU, 16 waves/CU.

typedef __attribute__((ext_vector_type(8))) short s8v;   // 8 bf16 = 4 VGPR
typedef __attribute__((ext_vector_type(4))) float f4v;   // MFMA C/D

#define MFMA16(a, b, c) __builtin_amdgcn_mfma_f32_16x16x32_bf16(a, b, c, 0, 0, 0)

__device__ __forceinline__ ushort f2bf(float x) {
    unsigned u = __float_as_uint(x);
    return (ushort)((u + 0x7FFF + ((u >> 16) & 1)) >> 16);  // RNE
}
__device__ __forceinline__ void split2(float x, ushort& h, ushort& l) {
    h = f2bf(x);
    float hf = __uint_as_float(((unsigned)h) << 16);
    l = f2bf(x - hf);
}

// ---------------------------------------------------------------- pack_wt ----
// W[k][n] fp32 -> Wt_hi[n][k], Wt_lo[n][k] bf16 (transpose + split), 1024x1024.
__global__ __launch_bounds__(256) void pack_wt(const float* __restrict__ W,
                                               ushort* __restrict__ Wt_hi,
                                               ushort* __restrict__ Wt_lo) {
    __shared__ float tile[32][36];
    const int t = threadIdx.x;
    const int n0 = blockIdx.x * 32, k0 = blockIdx.y * 32;
    {
        const int kr = t >> 3, c4 = (t & 7) * 4;
        float4 v = *(const float4*)&W[(size_t)(k0 + kr) * 1024 + n0 + c4];
        *(float4*)&tile[kr][c4] = v;
    }
    __syncthreads();
    {
        const int n = t >> 3, k4 = (t & 7) * 4;
        ushort4 h, l;
        split2(tile[k4 + 0][n], h.x, l.x);
        split2(tile[k4 + 1][n], h.y, l.y);
        split2(tile[k4 + 2][n], h.z, l.z);
        split2(tile[k4 + 3][n], h.w, l.w);
        *(ushort4*)&Wt_hi[(size_t)(n0 + n) * 1024 + k0 + k4] = h;
        *(ushort4*)&Wt_lo[(size_t)(n0 + n) * 1024 + k0 + k4] = l;
    }
}

// -------------------------------------------------------------- gemm_proj ----
// X(4096x1024 fp32) @ W (via Wt bf16 [n][k]) + bias -> head-split bf16 out.
// 128x128 tile, BK=32, 256 thr (4 waves, each 64x64 = 4x4 tiles of 16x16x32).
#define PROJ_LDSTRIDE 40
template <bool SPLIT>
__global__ __launch_bounds__(256, 2) void gemm_proj_mfma(
    const float* __restrict__ X, const ushort* __restrict__ Wt_hi,
    const ushort* __restrict__ Wt_lo, const float* __restrict__ bias,
    ushort* __restrict__ Yhi, ushort* __restrict__ Ylo) {
    __shared__ ushort As_hi[128 * PROJ_LDSTRIDE];
    __shared__ ushort As_lo[128 * PROJ_LDSTRIDE];
    __shared__ ushort Bs_hi[128 * PROJ_LDSTRIDE];
    __shared__ ushort Bs_lo[128 * PROJ_LDSTRIDE];

    const int t = threadIdx.x;
    const int lane = t & 63, w = t >> 6;
    const int wm = (w & 1) * 64, wn = (w >> 1) * 64;
    const int fr = lane & 15, q8 = (lane >> 4) * 8;
    const int row0 = blockIdx.y * 128, col0 = blockIdx.x * 128;

    const int srow = t >> 1, skb = (t & 1) * 16;

    f4v acc[4][4] = {};

    for (int k0 = 0; k0 < 1024; k0 += 32) {
        {
            const float* xp = &X[(size_t)(row0 + srow) * 1024 + k0 + skb];
#pragma unroll
            for (int j = 0; j < 4; ++j) {
                float4 x4 = *(const float4*)&xp[4 * j];
                ushort4 h, l;
                split2(x4.x, h.x, l.x);
                split2(x4.y, h.y, l.y);
                split2(x4.z, h.z, l.z);
                split2(x4.w, h.w, l.w);
                *(ushort4*)&As_hi[srow * PROJ_LDSTRIDE + skb + 4 * j] = h;
                if (SPLIT) *(ushort4*)&As_lo[srow * PROJ_LDSTRIDE + skb + 4 * j] = l;
            }
        }
        {
            const ushort* bp = &Wt_hi[(size_t)(col0 + srow) * 1024 + k0 + skb];
            *(uint4*)&Bs_hi[srow * PROJ_LDSTRIDE + skb] = *(const uint4*)bp;
            *(uint4*)&Bs_hi[srow * PROJ_LDSTRIDE + skb + 8] = *(const uint4*)(bp + 8);
            if (SPLIT) {
                const ushort* bl = &Wt_lo[(size_t)(col0 + srow) * 1024 + k0 + skb];
                *(uint4*)&Bs_lo[srow * PROJ_LDSTRIDE + skb] = *(const uint4*)bl;
                *(uint4*)&Bs_lo[srow * PROJ_LDSTRIDE + skb + 8] = *(const uint4*)(bl + 8);
            }
        }
        __syncthreads();

        s8v a_hi[4], a_lo[4], b_hi[4], b_lo[4];
#pragma unroll
        for (int mi = 0; mi < 4; ++mi) {
            a_hi[mi] = *(const s8v*)&As_hi[(wm + mi * 16 + fr) * PROJ_LDSTRIDE + q8];
            if (SPLIT) a_lo[mi] = *(const s8v*)&As_lo[(wm + mi * 16 + fr) * PROJ_LDSTRIDE + q8];
        }
#pragma unroll
        for (int ni = 0; ni < 4; ++ni) {
            b_hi[ni] = *(const s8v*)&Bs_hi[(wn + ni * 16 + fr) * PROJ_LDSTRIDE + q8];
            if (SPLIT) b_lo[ni] = *(const s8v*)&Bs_lo[(wn + ni * 16 + fr) * PROJ_LDSTRIDE + q8];
        }
#pragma unroll
        for (int mi = 0; mi < 4; ++mi)
#pragma unroll
            for (int ni = 0; ni < 4; ++ni) {
                acc[mi][ni] = MFMA16(a_hi[mi], b_hi[ni], acc[mi][ni]);
                if (SPLIT) {
                    acc[mi][ni] = MFMA16(a_hi[mi], b_lo[ni], acc[mi][ni]);
                    acc[mi][ni] = MFMA16(a_lo[mi], b_hi[ni], acc[mi][ni]);
                }
            }
        __syncthreads();
    }

#pragma unroll
    for (int mi = 0; mi < 4; ++mi)
#pragma unroll
        for (int ni = 0; ni < 4; ++ni)
#pragma unroll
            for (int r = 0; r < 4; ++r) {
                const int lr = wm + mi * 16 + (lane >> 4) * 4 + r;
                const int lc = wn + ni * 16 + fr;
                const int grow = row0 + lr;
                const int b = grow >> 10, ll = grow & 1023;
                const int gcol = col0 + lc;
                const int h = gcol >> 6, u = gcol & 63;
                const float val = acc[mi][ni][r] + bias[gcol];
                const size_t o = ((size_t)((b * 16 + h) * 1024 + ll)) * 64 + u;
                if (SPLIT) {
                    ushort hh, lll;
                    split2(val, hh, lll);
                    Yhi[o] = hh;
                    Ylo[o] = lll;
                } else {
                    Yhi[o] = f2bf(val);
                }
            }
}

// --------------------------------------------------------------- trans_vh ----
__global__ __launch_bounds__(256) void trans_vh(const ushort* __restrict__ vh,
                                                ushort* __restrict__ vhT) {
    __shared__ ushort st[64][72];
    const int t = threadIdx.x;
    const int bh = blockIdx.y, l0 = blockIdx.x * 64;
    {
        const int l = t >> 2, uc = (t & 3) * 16;
        const ushort* src = &vh[((size_t)bh * 1024 + l0 + l) * 64 + uc];
        *(uint4*)&st[l][uc] = *(const uint4*)src;
        *(uint4*)&st[l][uc + 8] = *(const uint4*)(src + 8);
    }
    __syncthreads();
    {
        const int u = t >> 2, lc = (t & 3) * 16;
        ushort tmp[16];
#pragma unroll
        for (int i = 0; i < 16; ++i) tmp[i] = st[lc + i][u];
        ushort* dst = &vhT[((size_t)bh * 64 + u) * 1024 + l0 + lc];
        *(uint4*)dst = *(uint4*)&tmp[0];
        *(uint4*)(dst + 8) = *(uint4*)&tmp[8];
    }
}

// ------------------------------------------------------------- attn_fused ----
// Block = one bh, 64 q-rows (4 q-tiles). 1024 threads = 16 waves:
//   wave w -> (qi = w>>2, ki = w&3).
// Phase 1 (logits): wave (qi,ki) computes q-rows [16qi,+16) x k-tiles
//   [16ki,+16) via swapped-operand MFMA (lane (g,fr): q-row = fr,
//   k-cols = nt*16+4g+{0..3}). The 4 waves sharing ki read IDENTICAL K
//   addresses near-simultaneously -> L1 serves 3 of 4 (4x L2-traffic cut).
// Phase 2 (softmax): lane-local max/sum, 2 shuffles, cross-wave via
//   redA/redB[ki][qi][row].
// Phase 3 (normalize): paired float4 attn stores (full 128B lines) + bf16 P
//   to 128 KB swizzled LDS.
// Phase 4 (ctx): wave (qi, ui=ki) computes rows [16qi,+16) x u [16ui,+16);
//   4 waves per ui share vhT reads (L1 dedup again).
__device__ __forceinline__ int pswz(int row, int b) {
    return row * 2048 + (b ^ ((row & 7) << 4) ^ ((row & 8) << 2));
}

__global__ __launch_bounds__(1024, 4) void attn_fused(
    const ushort* __restrict__ qh_hi, const ushort* __restrict__ qh_lo,
    const ushort* __restrict__ kh_hi, const ushort* __restrict__ kh_lo,
    const ushort* __restrict__ vhT, float* __restrict__ attn,
    float* __restrict__ ctx) {
    __shared__ ushort Pl[64 * 1024];  // 128 KB bf16 probs (64 q-rows)
    __shared__ float redA[4][4][16];  // [ki][qi][row] cross-wave max
    __shared__ float redB[4][4][16];  // [ki][qi][row] cross-wave sum

    const int t = threadIdx.x, lane = t & 63, w = t >> 6;
    const int qi = w >> 2, ki = w & 3;
    // XCD-bijective swizzle: 1024 blocks / 8 XCDs -> 128-block chunks; the 16
    // blocks of one bh stay on one XCD's L2.
    const int bid = blockIdx.x;
    const int sbid = (bid & 7) * 128 + (bid >> 3);
    const int bh = sbid >> 4, q0 = (sbid & 15) * 64;
    const int fr = lane & 15, g = lane >> 4, q8 = g * 8;
    const size_t hbase = (size_t)bh * 1024 * 64;
    const int qrow = q0 + 16 * qi + fr;  // this lane's q-row

    // Q fragments (B-operand): lane (g,fr) -> Q[qrow][q8+j], d-slices 0/1
    const ushort* qp = &qh_hi[hbase + (size_t)qrow * 64];
    const ushort* ql = &qh_lo[hbase + (size_t)qrow * 64];
    const s8v qb_h0 = *(const s8v*)(qp + q8), qb_h1 = *(const s8v*)(qp + 32 + q8);
    const s8v qb_l0 = *(const s8v*)(ql + q8), qb_l1 = *(const s8v*)(ql + 32 + q8);

    // ---- logits into registers: lg[i][r] = logits[q=qrow][k=(16ki+i)*16+4g+r]/8
    f4v lg[16];
#pragma unroll
    for (int i = 0; i < 16; ++i) {
        const int nt = 16 * ki + i;
        const ushort* kp = &kh_hi[hbase + (size_t)(nt * 16 + fr) * 64];
        const ushort* kl = &kh_lo[hbase + (size_t)(nt * 16 + fr) * 64];
        const s8v ka_h0 = *(const s8v*)(kp + q8), ka_h1 = *(const s8v*)(kp + 32 + q8);
        const s8v ka_l0 = *(const s8v*)(kl + q8), ka_l1 = *(const s8v*)(kl + 32 + q8);
        f4v a0 = {}, a1 = {}, a2 = {};
        a0 = MFMA16(ka_h0, qb_h0, a0);   // K_hi * Q_hi
        a0 = MFMA16(ka_h1, qb_h1, a0);
        a1 = MFMA16(ka_l0, qb_h0, a1);   // K_lo * Q_hi
        a1 = MFMA16(ka_l1, qb_h1, a1);
        a2 = MFMA16(ka_h0, qb_l0, a2);   // K_hi * Q_lo
        a2 = MFMA16(ka_h1, qb_l1, a2);
#pragma unroll
        for (int r = 0; r < 4; ++r) lg[i][r] = (a0[r] + a1[r] + a2[r]) * 0.125f;
    }

    // ---- row max: lane-local fold, 2 shuffles, cross-wave (over ki) via redA
    f4v mv = lg[0];
#pragma unroll
    for (int i = 1; i < 16; ++i) {
#pragma unroll
        for (int r = 0; r < 4; ++r) mv[r] = fmaxf(mv[r], lg[i][r]);
    }
    float m = fmaxf(fmaxf(mv[0], mv[1]), fmaxf(mv[2], mv[3]));
    m = fmaxf(m, __shfl_xor(m, 16));
    m = fmaxf(m, __shfl_xor(m, 32));
    if (lane < 16) redA[ki][qi][lane] = m;
    __syncthreads();
    const float m4 = fmaxf(fmaxf(redA[0][qi][fr], redA[1][qi][fr]),
                           fmaxf(redA[2][qi][fr], redA[3][qi][fr]));

    // ---- exp + row sum (fp32 exact)
    f4v sv = {0.f, 0.f, 0.f, 0.f};
#pragma unroll
    for (int i = 0; i < 16; ++i) {
#pragma unroll
        for (int r = 0; r < 4; ++r) {
            const float e = __expf(lg[i][r] - m4);
            lg[i][r] = e;
            sv[r] += e;
        }
    }
    float s = (sv[0] + sv[1]) + (sv[2] + sv[3]);
    s += __shfl_xor(s, 16);
    s += __shfl_xor(s, 32);
    if (lane < 16) redB[ki][qi][lane] = s;
    __syncthreads();
    const float inv =
        1.0f / (redB[0][qi][fr] + redB[1][qi][fr] + redB[2][qi][fr] + redB[3][qi][fr]);

    // ---- normalize: per pair j, two adjacent float4 stores complete one
    //      128B attn line per row; bf16 P to swizzled LDS alongside.
    char* Pb = (char*)Pl;
    const int prow = 16 * qi + fr;
    float* abase = attn + ((size_t)bh << 20) + (size_t)qrow * 1024;
#pragma unroll
    for (int j = 0; j < 8; ++j) {
        const int iA = 2 * j, iB = 2 * j + 1;
        const int ntA = 16 * ki + iA;
        const int colA = ntA * 16 + 4 * g, colB = colA + 16;
        float4 pA, pB;
        pA.x = lg[iA][0] * inv; pA.y = lg[iA][1] * inv;
        pA.z = lg[iA][2] * inv; pA.w = lg[iA][3] * inv;
        pB.x = lg[iB][0] * inv; pB.y = lg[iB][1] * inv;
        pB.z = lg[iB][2] * inv; pB.w = lg[iB][3] * inv;
        *(float4*)&abase[colA] = pA;  // same wave writes both halves of the
        *(float4*)&abase[colB] = pB;  // line back-to-back -> full-line merge
        ushort4 bA, bB;
        bA.x = f2bf(pA.x); bA.y = f2bf(pA.y); bA.z = f2bf(pA.z); bA.w = f2bf(pA.w);
        bB.x = f2bf(pB.x); bB.y = f2bf(pB.y); bB.z = f2bf(pB.z); bB.w = f2bf(pB.w);
        *(ushort4*)(Pb + pswz(prow, colA * 2)) = bA;
        *(ushort4*)(Pb + pswz(prow, colB * 2)) = bB;
    }
    __syncthreads();

    // ---- ctx: wave (qi, ui=ki) -> rows [16qi,+16) x u-cols [16ui,+16);
    //      A = P bf16 from LDS, B = vhT (shared by 4 qi-waves -> L1 dedup)
    const int ui = ki;
    f4v cacc = {};
    const ushort* vp = &vhT[hbase + (size_t)(ui * 16 + fr) * 1024];
#pragma unroll 4
    for (int ks = 0; ks < 32; ++ks) {
        const s8v a = *(const s8v*)(Pb + pswz(prow, ks * 64 + q8 * 2));
        const s8v b = *(const s8v*)(vp + ks * 32 + q8);
        cacc = MFMA16(a, b, cacc);
    }
#pragma unroll
    for (int r = 0; r < 4; ++r)
        ctx[((size_t)bh * 1024 + q0 + 16 * qi + 4 * g + r) * 64 + ui * 16 + fr] =
            cacc[r];
}

// --------------------------------------------------------------- gemm_out ----
#define LDS_PAD 68
__global__ __launch_bounds__(256) void gemm_out(const float* __restrict__ ctx,
                                                const float* __restrict__ wo,
                                                const float* __restrict__ bo,
                                                float* __restrict__ out) {
    __shared__ float As[16][LDS_PAD];
    __shared__ float Bs[16][LDS_PAD];
    const int t = threadIdx.x;
    const int tx = t & 15, ty = t >> 4;
    const int row0 = blockIdx.y * 64;

    const int am = t >> 2, ak4 = t & 3;
    const int bk = t >> 4, bn4 = t & 15;

    float acc[4][4] = {};
    for (int k0 = 0; k0 < 1024; k0 += 16) {
        const int r = row0 + am;
        const int b = r >> 10, l = r & 1023;
        const int c = k0 + ak4 * 4;
        const int h = c >> 6, d = c & 63;
        float4 a = *(const float4*)&ctx[(size_t)((b * 16 + h) * 1024 + l) * 64 + d];
        float4 bvv = *(const float4*)&wo[(size_t)(k0 + bk) * 64 + bn4 * 4];
        As[ak4 * 4 + 0][am] = a.x; As[ak4 * 4 + 1][am] = a.y;
        As[ak4 * 4 + 2][am] = a.z; As[ak4 * 4 + 3][am] = a.w;
        Bs[bk][bn4 * 4 + 0] = bvv.x; Bs[bk][bn4 * 4 + 1] = bvv.y;
        Bs[bk][bn4 * 4 + 2] = bvv.z; Bs[bk][bn4 * 4 + 3] = bvv.w;
        __syncthreads();
#pragma unroll
        for (int kk = 0; kk < 16; ++kk) {
            float av[4], bv[4];
#pragma unroll
            for (int i = 0; i < 4; ++i) av[i] = As[kk][ty * 4 + i];
#pragma unroll
            for (int j = 0; j < 4; ++j) bv[j] = Bs[kk][tx * 4 + j];
#pragma unroll
            for (int i = 0; i < 4; ++i)
#pragma unroll
                for (int j = 0; j < 4; ++j) acc[i][j] += av[i] * bv[j];
        }
        __syncthreads();
    }
#pragma unroll
    for (int i = 0; i < 4; ++i) {
        const int r = row0 + ty * 4 + i;
#pragma unroll
        for (int j = 0; j < 4; ++j) {
            const int u = tx * 4 + j;
            out[(size_t)r * 64 + u] = acc[i][j] + bo[u];
        }
    }
}

extern "C" void kernel_launch(void* const* d_in, const int* in_sizes, int n_in,
                              void* d_out, int out_size, void* d_ws, size_t ws_size,
                              hipStream_t stream) {
    const float* v_in = (const float*)d_in[0];
    const float* k_in = (const float*)d_in[1];
    const float* q_in = (const float*)d_in[2];
    const float* wq = (const float*)d_in[3];
    const float* bq = (const float*)d_in[4];
    const float* wk = (const float*)d_in[5];
    const float* bk = (const float*)d_in[6];
    const float* wv = (const float*)d_in[7];
    const float* bv = (const float*)d_in[8];
    const float* wo = (const float*)d_in[9];
    const float* bo = (const float*)d_in[10];

    float* out = (float*)d_out;
    float* attn = out + 262144;

    char* w8 = (char*)d_ws;
    const size_t MB = 1u << 20;
    ushort* wtq_hi = (ushort*)(w8 + 0 * MB);
    ushort* wtq_lo = (ushort*)(w8 + 2 * MB);
    ushort* wtk_hi = (ushort*)(w8 + 4 * MB);
    ushort* wtk_lo = (ushort*)(w8 + 6 * MB);
    ushort* wtv_hi = (ushort*)(w8 + 8 * MB);
    ushort* wtv_lo = (ushort*)(w8 + 10 * MB);
    ushort* qh_hi = (ushort*)(w8 + 12 * MB);
    ushort* qh_lo = (ushort*)(w8 + 20 * MB);
    ushort* kh_hi = (ushort*)(w8 + 28 * MB);
    ushort* kh_lo = (ushort*)(w8 + 36 * MB);
    ushort* vh_hi = (ushort*)(w8 + 44 * MB);
    ushort* vh_lo = (ushort*)(w8 + 52 * MB);
    ushort* vhT = (ushort*)(w8 + 60 * MB);
    float* ctx = (float*)(w8 + 68 * MB);

    dim3 blk(256);
    pack_wt<<<dim3(32, 32), blk, 0, stream>>>(wq, wtq_hi, wtq_lo);
    pack_wt<<<dim3(32, 32), blk, 0, stream>>>(wk, wtk_hi, wtk_lo);
    pack_wt<<<dim3(32, 32), blk, 0, stream>>>(wv, wtv_hi, wtv_lo);

    gemm_proj_mfma<true><<<dim3(8, 32), blk, 0, stream>>>(q_in, wtq_hi, wtq_lo, bq, qh_hi, qh_lo);
    gemm_proj_mfma<true><<<dim3(8, 32), blk, 0, stream>>>(k_in, wtk_hi, wtk_lo, bk, kh_hi, kh_lo);
    gemm_proj_mfma<false><<<dim3(8, 32), blk, 0, stream>>>(v_in, wtv_hi, wtv_lo, bv, vh_hi, vh_lo);

    trans_vh<<<dim3(16, 64), blk, 0, stream>>>(vh_hi, vhT);

    attn_fused<<<dim3(1024), dim3(1024), 0, stream>>>(qh_hi, qh_lo, kh_hi, kh_lo, vhT, attn, ctx);

    gemm_out<<<dim3(1, 64), blk, 0, stream>>>(ctx, wo, bo, out);
}

// Round 6
// 626.259 us; speedup vs baseline: 1.2478x; 1.2478x over previous
//
#include <hip/hip_runtime.h>
#include <hip/hip_bf16.h>

// MultiHeadAttention  B=4, L=1024, H=16, U=64, D_IN=1024, D_MODEL=1024
// Round 6: attack the non-attn ~500 µs + attn load-chain ILP.
//   - pack_wt x3   -> pack_wt_all (1 launch, grid z=3)
//   - gemm_proj x3 -> gemm_proj_all (1 launch, grid (8,32,3)=768 blocks:
//                     2-3 blocks/CU resident vs 1 before; q/k split path,
//                     v non-split path via template dispatch on blockIdx.z)
//   - gemm_out: 64 -> 256 blocks (N split into 4x16-col panels)
//   - attn_fused: R4 structure (best: 232us) + explicit 2-deep double-buffer
//     prefetch of K-tile frags (logits) and vhT frags (ctx);
//     launch_bounds(256,3) for register headroom. Tests the serial
//     load->MFMA chain hypothesis (occupancy/instr-count/store-pattern all
//     falsified in R1-R5).

typedef __attribute__((ext_vector_type(8))) short s8v;   // 8 bf16 = 4 VGPR
typedef __attribute__((ext_vector_type(4))) float f4v;   // MFMA C/D

#define MFMA16(a, b, c) __builtin_amdgcn_mfma_f32_16x16x32_bf16(a, b, c, 0, 0, 0)

__device__ __forceinline__ ushort f2bf(float x) {
    unsigned u = __float_as_uint(x);
    return (ushort)((u + 0x7FFF + ((u >> 16) & 1)) >> 16);  // RNE
}
__device__ __forceinline__ void split2(float x, ushort& h, ushort& l) {
    h = f2bf(x);
    float hf = __uint_as_float(((unsigned)h) << 16);
    l = f2bf(x - hf);
}

// ------------------------------------------------------------ pack_wt_all ----
// W[k][n] fp32 -> Wt_hi[n][k], Wt_lo[n][k] bf16 (transpose + split).
// blockIdx.z selects q/k/v weight set.
__global__ __launch_bounds__(256) void pack_wt_all(
    const float* __restrict__ Wq, const float* __restrict__ Wk,
    const float* __restrict__ Wv, ushort* __restrict__ Hq,
    ushort* __restrict__ Lq, ushort* __restrict__ Hk, ushort* __restrict__ Lk,
    ushort* __restrict__ Hv, ushort* __restrict__ Lv) {
    const int z = blockIdx.z;
    const float* W = (z == 0) ? Wq : (z == 1) ? Wk : Wv;
    ushort* WH = (z == 0) ? Hq : (z == 1) ? Hk : Hv;
    ushort* WL = (z == 0) ? Lq : (z == 1) ? Lk : Lv;

    __shared__ float tile[32][36];
    const int t = threadIdx.x;
    const int n0 = blockIdx.x * 32, k0 = blockIdx.y * 32;
    {
        const int kr = t >> 3, c4 = (t & 7) * 4;
        float4 v = *(const float4*)&W[(size_t)(k0 + kr) * 1024 + n0 + c4];
        *(float4*)&tile[kr][c4] = v;
    }
    __syncthreads();
    {
        const int n = t >> 3, k4 = (t & 7) * 4;
        ushort4 h, l;
        split2(tile[k4 + 0][n], h.x, l.x);
        split2(tile[k4 + 1][n], h.y, l.y);
        split2(tile[k4 + 2][n], h.z, l.z);
        split2(tile[k4 + 3][n], h.w, l.w);
        *(ushort4*)&WH[(size_t)(n0 + n) * 1024 + k0 + k4] = h;
        *(ushort4*)&WL[(size_t)(n0 + n) * 1024 + k0 + k4] = l;
    }
}

// ----------------------------------------------------------- gemm_proj_all ----
// X(4096x1024 fp32) @ W (via Wt bf16 [n][k]) + bias -> head-split bf16 out.
// 128x128 tile, BK=32, 256 thr. One launch, grid (8,32,3); z=0,1 -> split
// (Q,K), z=2 -> single-pass (V).
#define PROJ_LDSTRIDE 40
template <bool SPLIT>
__device__ __forceinline__ void proj_body(
    ushort* __restrict__ As_hi, ushort* __restrict__ As_lo,
    ushort* __restrict__ Bs_hi, ushort* __restrict__ Bs_lo,
    const float* __restrict__ X, const ushort* __restrict__ Wt_hi,
    const ushort* __restrict__ Wt_lo, const float* __restrict__ bias,
    ushort* __restrict__ Yhi, ushort* __restrict__ Ylo) {
    const int t = threadIdx.x;
    const int lane = t & 63, w = t >> 6;
    const int wm = (w & 1) * 64, wn = (w >> 1) * 64;
    const int fr = lane & 15, q8 = (lane >> 4) * 8;
    const int row0 = blockIdx.y * 128, col0 = blockIdx.x * 128;

    const int srow = t >> 1, skb = (t & 1) * 16;

    f4v acc[4][4] = {};

    for (int k0 = 0; k0 < 1024; k0 += 32) {
        {
            const float* xp = &X[(size_t)(row0 + srow) * 1024 + k0 + skb];
#pragma unroll
            for (int j = 0; j < 4; ++j) {
                float4 x4 = *(const float4*)&xp[4 * j];
                ushort4 h, l;
                split2(x4.x, h.x, l.x);
                split2(x4.y, h.y, l.y);
                split2(x4.z, h.z, l.z);
                split2(x4.w, h.w, l.w);
                *(ushort4*)&As_hi[srow * PROJ_LDSTRIDE + skb + 4 * j] = h;
                if (SPLIT) *(ushort4*)&As_lo[srow * PROJ_LDSTRIDE + skb + 4 * j] = l;
            }
        }
        {
            const ushort* bp = &Wt_hi[(size_t)(col0 + srow) * 1024 + k0 + skb];
            *(uint4*)&Bs_hi[srow * PROJ_LDSTRIDE + skb] = *(const uint4*)bp;
            *(uint4*)&Bs_hi[srow * PROJ_LDSTRIDE + skb + 8] = *(const uint4*)(bp + 8);
            if (SPLIT) {
                const ushort* bl = &Wt_lo[(size_t)(col0 + srow) * 1024 + k0 + skb];
                *(uint4*)&Bs_lo[srow * PROJ_LDSTRIDE + skb] = *(const uint4*)bl;
                *(uint4*)&Bs_lo[srow * PROJ_LDSTRIDE + skb + 8] = *(const uint4*)(bl + 8);
            }
        }
        __syncthreads();

        s8v a_hi[4], a_lo[4], b_hi[4], b_lo[4];
#pragma unroll
        for (int mi = 0; mi < 4; ++mi) {
            a_hi[mi] = *(const s8v*)&As_hi[(wm + mi * 16 + fr) * PROJ_LDSTRIDE + q8];
            if (SPLIT) a_lo[mi] = *(const s8v*)&As_lo[(wm + mi * 16 + fr) * PROJ_LDSTRIDE + q8];
        }
#pragma unroll
        for (int ni = 0; ni < 4; ++ni) {
            b_hi[ni] = *(const s8v*)&Bs_hi[(wn + ni * 16 + fr) * PROJ_LDSTRIDE + q8];
            if (SPLIT) b_lo[ni] = *(const s8v*)&Bs_lo[(wn + ni * 16 + fr) * PROJ_LDSTRIDE + q8];
        }
#pragma unroll
        for (int mi = 0; mi < 4; ++mi)
#pragma unroll
            for (int ni = 0; ni < 4; ++ni) {
                acc[mi][ni] = MFMA16(a_hi[mi], b_hi[ni], acc[mi][ni]);
                if (SPLIT) {
                    acc[mi][ni] = MFMA16(a_hi[mi], b_lo[ni], acc[mi][ni]);
                    acc[mi][ni] = MFMA16(a_lo[mi], b_hi[ni], acc[mi][ni]);
                }
            }
        __syncthreads();
    }

#pragma unroll
    for (int mi = 0; mi < 4; ++mi)
#pragma unroll
        for (int ni = 0; ni < 4; ++ni)
#pragma unroll
            for (int r = 0; r < 4; ++r) {
                const int lr = wm + mi * 16 + (lane >> 4) * 4 + r;
                const int lc = wn + ni * 16 + fr;
                const int grow = row0 + lr;
                const int b = grow >> 10, ll = grow & 1023;
                const int gcol = col0 + lc;
                const int h = gcol >> 6, u = gcol & 63;
                const float val = acc[mi][ni][r] + bias[gcol];
                const size_t o = ((size_t)((b * 16 + h) * 1024 + ll)) * 64 + u;
                if (SPLIT) {
                    ushort hh, lll;
                    split2(val, hh, lll);
                    Yhi[o] = hh;
                    Ylo[o] = lll;
                } else {
                    Yhi[o] = f2bf(val);
                }
            }
}

__global__ __launch_bounds__(256, 2) void gemm_proj_all(
    const float* __restrict__ q_in, const float* __restrict__ k_in,
    const float* __restrict__ v_in, const ushort* __restrict__ wtq_hi,
    const ushort* __restrict__ wtq_lo, const ushort* __restrict__ wtk_hi,
    const ushort* __restrict__ wtk_lo, const ushort* __restrict__ wtv_hi,
    const ushort* __restrict__ wtv_lo, const float* __restrict__ bq,
    const float* __restrict__ bk, const float* __restrict__ bv,
    ushort* __restrict__ qh_hi, ushort* __restrict__ qh_lo,
    ushort* __restrict__ kh_hi, ushort* __restrict__ kh_lo,
    ushort* __restrict__ vh_hi, ushort* __restrict__ vh_lo) {
    __shared__ ushort As_hi[128 * PROJ_LDSTRIDE];
    __shared__ ushort As_lo[128 * PROJ_LDSTRIDE];
    __shared__ ushort Bs_hi[128 * PROJ_LDSTRIDE];
    __shared__ ushort Bs_lo[128 * PROJ_LDSTRIDE];
    const int z = blockIdx.z;
    if (z == 0)
        proj_body<true>(As_hi, As_lo, Bs_hi, Bs_lo, q_in, wtq_hi, wtq_lo, bq,
                        qh_hi, qh_lo);
    else if (z == 1)
        proj_body<true>(As_hi, As_lo, Bs_hi, Bs_lo, k_in, wtk_hi, wtk_lo, bk,
                        kh_hi, kh_lo);
    else
        proj_body<false>(As_hi, As_lo, Bs_hi, Bs_lo, v_in, wtv_hi, wtv_lo, bv,
                         vh_hi, vh_lo);
}

// --------------------------------------------------------------- trans_vh ----
__global__ __launch_bounds__(256) void trans_vh(const ushort* __restrict__ vh,
                                                ushort* __restrict__ vhT) {
    __shared__ ushort st[64][72];
    const int t = threadIdx.x;
    const int bh = blockIdx.y, l0 = blockIdx.x * 64;
    {
        const int l = t >> 2, uc = (t & 3) * 16;
        const ushort* src = &vh[((size_t)bh * 1024 + l0 + l) * 64 + uc];
        *(uint4*)&st[l][uc] = *(const uint4*)src;
        *(uint4*)&st[l][uc + 8] = *(const uint4*)(src + 8);
    }
    __syncthreads();
    {
        const int u = t >> 2, lc = (t & 3) * 16;
        ushort tmp[16];
#pragma unroll
        for (int i = 0; i < 16; ++i) tmp[i] = st[lc + i][u];
        ushort* dst = &vhT[((size_t)bh * 64 + u) * 1024 + l0 + lc];
        *(uint4*)dst = *(uint4*)&tmp[0];
        *(uint4*)(dst + 8) = *(uint4*)&tmp[8];
    }
}

// ------------------------------------------------------------- attn_fused ----
// R4 structure (16 q-rows/block, 4096 blocks, 4 waves) + explicit 2-deep
// double-buffered prefetch of K-tile fragments (logits) and vhT fragments
// (ctx). Tile map: wave w, iter i -> nt = 2w + 8*(i>>1) + (i&1); pairs give
// full 128B attn lines per row.
__device__ __forceinline__ int pswz(int row, int b) {
    return row * 2048 + (b ^ ((row & 7) << 4) ^ ((row & 8) << 2));
}

__global__ __launch_bounds__(256, 3) void attn_fused(
    const ushort* __restrict__ qh_hi, const ushort* __restrict__ qh_lo,
    const ushort* __restrict__ kh_hi, const ushort* __restrict__ kh_lo,
    const ushort* __restrict__ vhT, float* __restrict__ attn,
    float* __restrict__ ctx) {
    __shared__ ushort Pl[16 * 1024];  // 32 KB bf16 probs
    __shared__ float redA[4][16];     // cross-wave max
    __shared__ float redB[4][16];     // cross-wave sum

    const int t = threadIdx.x, lane = t & 63, w = t >> 6;
    const int bid = blockIdx.x;
    const int sbid = (bid & 7) * 512 + (bid >> 3);
    const int bh = sbid >> 6, q0 = (sbid & 63) * 16;
    const int fr = lane & 15, g = lane >> 4, q8 = g * 8;
    const size_t hbase = (size_t)bh * 1024 * 64;

    // Q fragments (B-operand): lane (g,fr) -> Q[q0+fr][q8+j], d-slices 0/1
    const ushort* qp = &qh_hi[hbase + (size_t)(q0 + fr) * 64];
    const ushort* ql = &qh_lo[hbase + (size_t)(q0 + fr) * 64];
    const s8v qb_h0 = *(const s8v*)(qp + q8), qb_h1 = *(const s8v*)(qp + 32 + q8);
    const s8v qb_l0 = *(const s8v*)(ql + q8), qb_l1 = *(const s8v*)(ql + 32 + q8);

    // K-tile byte offset for iter i
    auto kofs = [&](int i) {
        const int nt = 2 * w + 8 * (i >> 1) + (i & 1);
        return hbase + (size_t)(nt * 16 + fr) * 64;
    };

    // ---- logits with 2-deep prefetch: lg[i][r] = logits[q=fr][k=nt*16+4g+r]/8
    f4v lg[16];
    s8v kh0[2], kh1[2], kl0[2], kl1[2];
    {
        const size_t o0 = kofs(0);
        kh0[0] = *(const s8v*)(kh_hi + o0 + q8);
        kh1[0] = *(const s8v*)(kh_hi + o0 + 32 + q8);
        kl0[0] = *(const s8v*)(kh_lo + o0 + q8);
        kl1[0] = *(const s8v*)(kh_lo + o0 + 32 + q8);
    }
#pragma unroll
    for (int i = 0; i < 16; ++i) {
        const int cur = i & 1, nxt = cur ^ 1;
        if (i < 15) {
            const size_t on = kofs(i + 1);
            kh0[nxt] = *(const s8v*)(kh_hi + on + q8);
            kh1[nxt] = *(const s8v*)(kh_hi + on + 32 + q8);
            kl0[nxt] = *(const s8v*)(kh_lo + on + q8);
            kl1[nxt] = *(const s8v*)(kh_lo + on + 32 + q8);
        }
        f4v a0 = {}, a1 = {}, a2 = {};
        a0 = MFMA16(kh0[cur], qb_h0, a0);   // K_hi * Q_hi
        a0 = MFMA16(kh1[cur], qb_h1, a0);
        a1 = MFMA16(kl0[cur], qb_h0, a1);   // K_lo * Q_hi
        a1 = MFMA16(kl1[cur], qb_h1, a1);
        a2 = MFMA16(kh0[cur], qb_l0, a2);   // K_hi * Q_lo
        a2 = MFMA16(kh1[cur], qb_l1, a2);
#pragma unroll
        for (int r = 0; r < 4; ++r) lg[i][r] = (a0[r] + a1[r] + a2[r]) * 0.125f;
    }

    // ---- row max: lane-local fold, 2 shuffles, cross-wave via redA
    f4v mv = lg[0];
#pragma unroll
    for (int i = 1; i < 16; ++i) {
#pragma unroll
        for (int r = 0; r < 4; ++r) mv[r] = fmaxf(mv[r], lg[i][r]);
    }
    float m = fmaxf(fmaxf(mv[0], mv[1]), fmaxf(mv[2], mv[3]));
    m = fmaxf(m, __shfl_xor(m, 16));
    m = fmaxf(m, __shfl_xor(m, 32));
    if (lane < 16) redA[w][lane] = m;
    __syncthreads();
    const float m4 = fmaxf(fmaxf(redA[0][fr], redA[1][fr]),
                           fmaxf(redA[2][fr], redA[3][fr]));

    // ---- exp + row sum (fp32 exact)
    f4v sv = {0.f, 0.f, 0.f, 0.f};
#pragma unroll
    for (int i = 0; i < 16; ++i) {
#pragma unroll
        for (int r = 0; r < 4; ++r) {
            const float e = __expf(lg[i][r] - m4);
            lg[i][r] = e;
            sv[r] += e;
        }
    }
    float s = (sv[0] + sv[1]) + (sv[2] + sv[3]);
    s += __shfl_xor(s, 16);
    s += __shfl_xor(s, 32);
    if (lane < 16) redB[w][lane] = s;
    __syncthreads();
    const float inv = 1.0f / (redB[0][fr] + redB[1][fr] + redB[2][fr] + redB[3][fr]);

    // ---- normalize: per pair j, two adjacent float4 stores complete one
    //      128B attn line per row; bf16 P to swizzled LDS alongside.
    char* Pb = (char*)Pl;
    float* abase = attn + ((size_t)bh << 20) + (size_t)(q0 + fr) * 1024;
#pragma unroll
    for (int j = 0; j < 8; ++j) {
        const int iA = 2 * j, iB = 2 * j + 1;
        const int ntA = 2 * w + 8 * j;
        const int colA = ntA * 16 + 4 * g, colB = colA + 16;
        float4 pA, pB;
        pA.x = lg[iA][0] * inv; pA.y = lg[iA][1] * inv;
        pA.z = lg[iA][2] * inv; pA.w = lg[iA][3] * inv;
        pB.x = lg[iB][0] * inv; pB.y = lg[iB][1] * inv;
        pB.z = lg[iB][2] * inv; pB.w = lg[iB][3] * inv;
        *(float4*)&abase[colA] = pA;
        *(float4*)&abase[colB] = pB;
        ushort4 bA, bB;
        bA.x = f2bf(pA.x); bA.y = f2bf(pA.y); bA.z = f2bf(pA.z); bA.w = f2bf(pA.w);
        bB.x = f2bf(pB.x); bB.y = f2bf(pB.y); bB.z = f2bf(pB.z); bB.w = f2bf(pB.w);
        *(ushort4*)(Pb + pswz(fr, colA * 2)) = bA;
        *(ushort4*)(Pb + pswz(fr, colB * 2)) = bB;
    }
    __syncthreads();

    // ---- ctx with 2-deep vhT prefetch: wave w -> u-tile w
    f4v cacc = {};
    const ushort* vp = &vhT[hbase + (size_t)(w * 16 + fr) * 1024];
    s8v vb[2];
    vb[0] = *(const s8v*)(vp + q8);
#pragma unroll
    for (int ks = 0; ks < 32; ++ks) {
        const int cur = ks & 1, nxt = cur ^ 1;
        if (ks < 31) vb[nxt] = *(const s8v*)(vp + (ks + 1) * 32 + q8);
        const s8v a = *(const s8v*)(Pb + pswz(fr, ks * 64 + q8 * 2));
        cacc = MFMA16(a, vb[cur], cacc);
    }
#pragma unroll
    for (int r = 0; r < 4; ++r)
        ctx[((size_t)bh * 1024 + q0 + 4 * g + r) * 64 + w * 16 + fr] = cacc[r];
}

// --------------------------------------------------------------- gemm_out ----
// concat(ctx fp32) @ wo + bo. Grid (4,64): 256 blocks of 64 rows x 16 cols.
__global__ __launch_bounds__(256) void gemm_out(const float* __restrict__ ctx,
                                                const float* __restrict__ wo,
                                                const float* __restrict__ bo,
                                                float* __restrict__ out) {
    __shared__ float As[16][68];
    __shared__ float Bs[16][20];
    const int t = threadIdx.x;
    const int row = t >> 2, c4 = (t & 3) * 4;
    const int n0 = blockIdx.x * 16;
    const int row0 = blockIdx.y * 64;

    const int am = t >> 2, ak4 = t & 3;

    float acc[4] = {};
    for (int k0 = 0; k0 < 1024; k0 += 16) {
        {
            const int r = row0 + am;
            const int b = r >> 10, l = r & 1023;
            const int c = k0 + ak4 * 4;
            const int h = c >> 6, d = c & 63;
            float4 a = *(const float4*)&ctx[(size_t)((b * 16 + h) * 1024 + l) * 64 + d];
            As[ak4 * 4 + 0][am] = a.x; As[ak4 * 4 + 1][am] = a.y;
            As[ak4 * 4 + 2][am] = a.z; As[ak4 * 4 + 3][am] = a.w;
        }
        if (t < 64) {
            const int bk = t >> 2, bc4 = (t & 3) * 4;
            float4 bv = *(const float4*)&wo[(size_t)(k0 + bk) * 64 + n0 + bc4];
            Bs[bk][bc4 + 0] = bv.x; Bs[bk][bc4 + 1] = bv.y;
            Bs[bk][bc4 + 2] = bv.z; Bs[bk][bc4 + 3] = bv.w;
        }
        __syncthreads();
#pragma unroll
        for (int kk = 0; kk < 16; ++kk) {
            const float a = As[kk][row];
            const float4 bv = *(const float4*)&Bs[kk][c4];
            acc[0] += a * bv.x; acc[1] += a * bv.y;
            acc[2] += a * bv.z; acc[3] += a * bv.w;
        }
        __syncthreads();
    }
#pragma unroll
    for (int j = 0; j < 4; ++j)
        out[(size_t)(row0 + row) * 64 + n0 + c4 + j] = acc[j] + bo[n0 + c4 + j];
}

extern "C" void kernel_launch(void* const* d_in, const int* in_sizes, int n_in,
                              void* d_out, int out_size, void* d_ws, size_t ws_size,
                              hipStream_t stream) {
    const float* v_in = (const float*)d_in[0];
    const float* k_in = (const float*)d_in[1];
    const float* q_in = (const float*)d_in[2];
    const float* wq = (const float*)d_in[3];
    const float* bq = (const float*)d_in[4];
    const float* wk = (const float*)d_in[5];
    const float* bk = (const float*)d_in[6];
    const float* wv = (const float*)d_in[7];
    const float* bv = (const float*)d_in[8];
    const float* wo = (const float*)d_in[9];
    const float* bo = (const float*)d_in[10];

    float* out = (float*)d_out;
    float* attn = out + 262144;

    char* w8 = (char*)d_ws;
    const size_t MB = 1u << 20;
    ushort* wtq_hi = (ushort*)(w8 + 0 * MB);
    ushort* wtq_lo = (ushort*)(w8 + 2 * MB);
    ushort* wtk_hi = (ushort*)(w8 + 4 * MB);
    ushort* wtk_lo = (ushort*)(w8 + 6 * MB);
    ushort* wtv_hi = (ushort*)(w8 + 8 * MB);
    ushort* wtv_lo = (ushort*)(w8 + 10 * MB);
    ushort* qh_hi = (ushort*)(w8 + 12 * MB);
    ushort* qh_lo = (ushort*)(w8 + 20 * MB);
    ushort* kh_hi = (ushort*)(w8 + 28 * MB);
    ushort* kh_lo = (ushort*)(w8 + 36 * MB);
    ushort* vh_hi = (ushort*)(w8 + 44 * MB);
    ushort* vh_lo = (ushort*)(w8 + 52 * MB);
    ushort* vhT = (ushort*)(w8 + 60 * MB);
    float* ctx = (float*)(w8 + 68 * MB);

    pack_wt_all<<<dim3(32, 32, 3), dim3(256), 0, stream>>>(
        wq, wk, wv, wtq_hi, wtq_lo, wtk_hi, wtk_lo, wtv_hi, wtv_lo);

    gemm_proj_all<<<dim3(8, 32, 3), dim3(256), 0, stream>>>(
        q_in, k_in, v_in, wtq_hi, wtq_lo, wtk_hi, wtk_lo, wtv_hi, wtv_lo,
        bq, bk, bv, qh_hi, qh_lo, kh_hi, kh_lo, vh_hi, vh_lo);

    trans_vh<<<dim3(16, 64), dim3(256), 0, stream>>>(vh_hi, vhT);

    attn_fused<<<dim3(4096), dim3(256), 0, stream>>>(qh_hi, qh_lo, kh_hi, kh_lo,
                                                     vhT, attn, ctx);

    gemm_out<<<dim3(4, 64), dim3(256), 0, stream>>>(ctx, wo, bo, out);
}